// Round 3
// baseline (88.963 us; speedup 1.0000x reference)
//
#include <hip/hip_runtime.h>

#define WID 256
#define HEI 256
#define CH  64
#define GRP 8
#define CPG 8
#define ND  9
#define HW  (HEI * WID)
#define SW  64      // strip width per wave
#define SPAD 80     // staged floats per channel: [W0-8, W0+71]

__global__ __launch_bounds__(256, 8)
void cost_volume_kernel(const float* __restrict__ L,
                        const float* __restrict__ R,
                        const float* __restrict__ disp,
                        float* __restrict__ out) {
    // 64 channels x 80 floats = 20480 B -> exactly 8 blocks/CU (160 KB)
    __shared__ float sR[CH * SPAD];

    const int bid   = blockIdx.x;        // b*1024 + h*4 + strip
    const int strip = bid & 3;
    const int h     = (bid >> 2) & 255;
    const int b     = bid >> 10;
    const int tid   = threadIdx.x;
    const int wv    = tid >> 6;          // wave 0..3 -> groups 2wv, 2wv+1
    const int lane  = tid & 63;
    const int W0    = strip * SW;

    // ---- wave-local staging: 16 channels x 80 floats = 5120 B = 5 instrs ----
    // linear float4 cell t = i*64+lane maps to (ch_local = t/20, seg = t%20)
    #pragma unroll
    for (int i = 0; i < 5; ++i) {
        const int t   = i * 64 + lane;
        const int cl  = t / 20;
        const int seg = t - cl * 20;
        int sx = W0 - 8 + seg * 4;
        sx = min(max(sx, 0), WID - 4);          // clamp inside the row (dup reads ok)
        const int ch = wv * 16 + cl;
        const float* gsrc = R + ((size_t)(b * CH + ch) * HEI + h) * WID + sx;
        __builtin_amdgcn_global_load_lds(
            (const __attribute__((address_space(1))) void*)gsrc,
            (__attribute__((address_space(3))) void*)
                ((char*)sR + (size_t)wv * 16 * SPAD * 4 + i * 1024),
            16, 0, 0);
    }

    const int w = W0 + lane;
    const float dv   = disp[(size_t)b * HW + (size_t)h * WID + w];
    const float base = (float)w - dv;
    const float fb   = floorf(base);
    const float frac = base - fb;
    const int   fib  = (int)fb;
    const bool interior = (fib >= 4) && (fib <= WID - 6);
    const int   sbase = fib - W0 + 4;    // strip index of tap j=0 (= fib-4 - (W0-8))

    const size_t lb    = ((size_t)(b * CH) * HEI + h) * WID + w;
    const size_t obase = ((size_t)(b * GRP) * ND) * HW + (size_t)h * WID + w;

    // wave-local drain of global_load_lds before reading own LDS quarter
    asm volatile("s_waitcnt vmcnt(0)" ::: "memory");

    #pragma unroll
    for (int gi = 0; gi < 2; ++gi) {
        const int g = wv * 2 + gi;

        float lf[CPG];
        #pragma unroll
        for (int k = 0; k < CPG; ++k)
            lf[k] = L[lb + (size_t)(g * CPG + k) * HW];

        // S[j] = sum_c l_c * r_c[fib-4+j], j = 0..9
        float S[10];
        #pragma unroll
        for (int j = 0; j < 10; ++j) S[j] = 0.0f;

        if (interior) {
            #pragma unroll
            for (int k = 0; k < CPG; ++k) {
                const float lv = lf[k];
                const float* p = sR + (g * CPG + k) * SPAD + sbase;
                #pragma unroll
                for (int j = 0; j < 10; ++j)
                    S[j] = fmaf(lv, p[j], S[j]);
            }
        } else {
            #pragma unroll
            for (int k = 0; k < CPG; ++k) {
                const float lv = lf[k];
                const float* p = sR + (g * CPG + k) * SPAD;
                #pragma unroll
                for (int j = 0; j < 10; ++j) {
                    int x = fib - 4 + j;
                    x = min(max(x, 0), WID - 1);
                    S[j] = fmaf(lv, p[x - W0 + 8], S[j]);
                }
            }
        }

        const size_t og = obase + (size_t)g * ND * HW;
        #pragma unroll
        for (int d = 0; d < ND; ++d) {
            const int x0 = fib + 4 - d;
            const int x1 = x0 + 1;
            const float wl = (x0 >= 0 && x0 < WID) ? (1.0f - frac) : 0.0f;
            const float wr = (x1 >= 0 && x1 < WID) ? frac : 0.0f;
            const float v = fmaf(wl, S[8 - d], wr * S[9 - d]) * 0.125f;
            __builtin_nontemporal_store(v, &out[og + (size_t)d * HW]);
        }
    }
}

extern "C" void kernel_launch(void* const* d_in, const int* in_sizes, int n_in,
                              void* d_out, int out_size, void* d_ws, size_t ws_size,
                              hipStream_t stream) {
    const float* feat_left  = (const float*)d_in[0];
    const float* feat_right = (const float*)d_in[1];
    const float* disp_init  = (const float*)d_in[2];
    float* out = (float*)d_out;

    dim3 grid(8 * HEI * 4);   // (b, h, strip)
    dim3 block(256);
    cost_volume_kernel<<<grid, block, 0, stream>>>(feat_left, feat_right, disp_init, out);
}